// Round 14
// baseline (334.921 us; speedup 1.0000x reference)
//
#include <hip/hip_runtime.h>
#include <math.h>

#define SEQ 8192
#define NEWBASE 8176     // SEQ - T
#define NS 4             // attn s-splits per (b, kv-head)

typedef short s16x4 __attribute__((ext_vector_type(4)));
typedef short s16x8 __attribute__((ext_vector_type(8)));
typedef float f32x4 __attribute__((ext_vector_type(4)));

__device__ __forceinline__ short f2bf(float f) {
  unsigned u = __float_as_uint(f);
  u += 0x7FFFu + ((u >> 16) & 1u);   // RNE
  return (short)(u >> 16);
}

__device__ __forceinline__ f32x4 mfma16(s16x8 a, s16x8 b, f32x4 c) {
  return __builtin_amdgcn_mfma_f32_16x16x32_bf16(a, b, c, 0, 0, 0);
}

// Workgroup barrier WITHOUT the vmcnt(0) drain of __syncthreads().
__device__ __forceinline__ void sync_nodrain() {
  __builtin_amdgcn_sched_barrier(0);
  asm volatile("s_waitcnt lgkmcnt(0)" ::: "memory");
  __builtin_amdgcn_s_barrier();
  __builtin_amdgcn_sched_barrier(0);
}

// ---- 64Mx128N tile GEMM, producer/consumer (attn7-style schedule) ----------
template<int KS>
__device__ __forceinline__
void gemm_tile_pc(const float* __restrict__ A, const float* __restrict__ Bw,
                  float* __restrict__ Cp, int ldc) {
  __shared__ short As[2][64 * 72];
  __shared__ short Bs[2][128 * 72];
  const int tid = threadIdx.x, lane = tid & 63, w = tid >> 6;
  const int l15 = lane & 15, l4 = lane >> 4;

  if (w < 4) {
    float4 aA[4], aB[4], bA[8], bB[8];
    auto issue = [&](int st, float4 (&ar)[4], float4 (&br)[8]) {
      const float* Ab = A + st * 64;
      const float* Bb = Bw + st * 64;
#pragma unroll
      for (int i = 0; i < 4; ++i) {
        int id = tid + i * 256;
        ar[i] = *(const float4*)(Ab + (size_t)(id >> 4) * 4096 + ((id & 15) << 2));
      }
#pragma unroll
      for (int i = 0; i < 8; ++i) {
        int id = tid + i * 256;
        br[i] = *(const float4*)(Bb + (size_t)(id >> 4) * 4096 + ((id & 15) << 2));
      }
    };
    auto convert = [&](int buf, const float4 (&ar)[4], const float4 (&br)[8]) {
#pragma unroll
      for (int i = 0; i < 4; ++i) {
        int id = tid + i * 256, row = id >> 4, c4 = (id & 15) << 2;
        s16x4 h = { f2bf(ar[i].x), f2bf(ar[i].y), f2bf(ar[i].z), f2bf(ar[i].w) };
        *(s16x4*)&As[buf][row * 72 + c4] = h;
      }
#pragma unroll
      for (int i = 0; i < 8; ++i) {
        int id = tid + i * 256, row = id >> 4, c4 = (id & 15) << 2;
        s16x4 h = { f2bf(br[i].x), f2bf(br[i].y), f2bf(br[i].z), f2bf(br[i].w) };
        *(s16x4*)&Bs[buf][row * 72 + c4] = h;
      }
    };

    issue(0, aA, bA);
    issue(1, aB, bB);
    convert(0, aA, bA);
    sync_nodrain();
    for (int c = 1; c < KS; c += 2) {
      convert(1, aB, bB);
      if (c + 1 < KS) issue(c + 1, aA, bA);
      sync_nodrain();
      if (c + 1 < KS) convert(0, aA, bA);
      if (c + 2 < KS) issue(c + 2, aB, bB);
      sync_nodrain();
    }
  } else {
    const int cw = w - 4;
    f32x4 acc[8] = {};
    sync_nodrain();
    for (int c = 0; c < KS; ++c) {
      const short* Ab = &As[c & 1][0];
      const short* Bb = &Bs[c & 1][0];
#pragma unroll
      for (int kk = 0; kk < 64; kk += 32) {
        s16x8 a = *(const s16x8*)&Ab[(cw * 16 + l15) * 72 + kk + l4 * 8];
#pragma unroll
        for (int nf = 0; nf < 8; ++nf) {
          s16x8 b = *(const s16x8*)&Bb[(nf * 16 + l15) * 72 + kk + l4 * 8];
          acc[nf] = mfma16(a, b, acc[nf]);
        }
      }
      sync_nodrain();
    }
#pragma unroll
    for (int nf = 0; nf < 8; ++nf)
#pragma unroll
      for (int r = 0; r < 4; ++r)
        Cp[(size_t)(cw * 16 + l4 * 4 + r) * ldc + nf * 16 + l15] = acc[nf][r];
  }
}

// fused QKV: grid (48, 4, 4); block (0,0,0) also builds the RoPE tables (fp64)
__global__ __launch_bounds__(512)
__attribute__((amdgpu_waves_per_eu(4, 4)))
void gemm_qkv(const float* __restrict__ x,
              const float* __restrict__ wq, const float* __restrict__ wk,
              const float* __restrict__ wv, float* __restrict__ part,
              const int* __restrict__ ipos,
              float* __restrict__ ctab, float* __restrict__ stab) {
  int bn = blockIdx.x, bm = blockIdx.y, sp = blockIdx.z;
  if (bn == 0 && bm == 0 && sp == 0) {
#pragma unroll
    for (int k = 0; k < 2; ++k) {
      int i = threadIdx.x + k * 512;       // 1024: t*64 + f
      int t = i >> 6, f = i & 63;
      double inv = exp(-((double)(2 * f) / 128.0) * log(500000.0));
      double ang = (double)ipos[t] * inv;
      ctab[i] = (float)cos(ang);
      stab[i] = (float)sin(ang);
    }
  }
  const float* Bw;
  if (bn < 32)      Bw = wq + (size_t)(bn * 128) * 4096;
  else if (bn < 40) Bw = wk + (size_t)((bn - 32) * 128) * 4096;
  else              Bw = wv + (size_t)((bn - 40) * 128) * 4096;
  const float* A = x + (size_t)(bm * 64) * 4096 + sp * 1024;
  float* Cp = part + (size_t)sp * (256 * 6144) + (size_t)(bm * 64) * 6144 + bn * 128;
  gemm_tile_pc<16>(A, Bw + sp * 1024, Cp, 6144);
}

// ---- out projection with MERGE FUSED into the A-producer -------------------
// A[row][gcol] = (sum_p pO[(blk+p)][qr*128 + d]) / (sum_p pL[(blk+p)*64+qr])
// where row=bm*64+rl -> (b,t); gcol -> h=(gcol>>7), g=h>>2, rep=h&3, qr=t*4+rep.
// B keeps the deep depth-2 payload; A-merge loads are L2-resident (just written).
// grid (32, 4, 4), 512 thr.
__global__ __launch_bounds__(512)
__attribute__((amdgpu_waves_per_eu(4, 4)))
void gemm_out_fused(const float* __restrict__ pO, const float* __restrict__ pL,
                    const float* __restrict__ wo, float* __restrict__ part) {
  __shared__ short As[2][64 * 72];
  __shared__ short Bs[2][128 * 72];
  const int bn = blockIdx.x, bm = blockIdx.y, sp = blockIdx.z;
  const int tid = threadIdx.x, lane = tid & 63, w = tid >> 6;
  const int l15 = lane & 15, l4 = lane >> 4;
  const float* Bw = wo + (size_t)(bn * 128) * 4096 + sp * 1024;
  float* Cp = part + (size_t)sp * (256 * 4096) + (size_t)(bm * 64) * 4096 + bn * 128;

  if (w < 4) {
    // -------- producers --------
    float4 bA[8], bB[8];
    auto issueB = [&](int st, float4 (&br)[8]) {
      const float* Bb = Bw + st * 64;
#pragma unroll
      for (int i = 0; i < 8; ++i) {
        int id = tid + i * 256;
        br[i] = *(const float4*)(Bb + (size_t)(id >> 4) * 4096 + ((id & 15) << 2));
      }
    };
    auto convert = [&](int buf, int st, const float4 (&br)[8]) {
      // A-merge (L2-resident pO/pL) + bf16 convert
#pragma unroll
      for (int i = 0; i < 4; ++i) {
        int id = tid + i * 256, rl = id >> 4, c4 = (id & 15) << 2;
        int gcol = sp * 1024 + st * 64 + c4;
        int row = bm * 64 + rl, bb = row >> 4, t = row & 15;
        int h = gcol >> 7, g = h >> 2, rep = h & 3;
        int qr = t * 4 + rep;
        int blk = (bb * 8 + g) * NS;
        const float* pp = pO + (size_t)blk * 8192 + qr * 128 + (gcol & 127);
        f32x4 s0 = *(const f32x4*)pp;
        f32x4 s1 = *(const f32x4*)(pp + 8192);
        f32x4 s2 = *(const f32x4*)(pp + 16384);
        f32x4 s3 = *(const f32x4*)(pp + 24576);
        const float* lp = pL + blk * 64 + qr;
        float den = lp[0] + lp[64] + lp[128] + lp[192];
        f32x4 s = (s0 + s1) + (s2 + s3);
        float rd = 1.0f / den;
        s16x4 hh = { f2bf(s[0] * rd), f2bf(s[1] * rd),
                     f2bf(s[2] * rd), f2bf(s[3] * rd) };
        *(s16x4*)&As[buf][rl * 72 + c4] = hh;
      }
#pragma unroll
      for (int i = 0; i < 8; ++i) {
        int id = tid + i * 256, rowb = id >> 4, c4 = (id & 15) << 2;
        s16x4 h = { f2bf(br[i].x), f2bf(br[i].y), f2bf(br[i].z), f2bf(br[i].w) };
        *(s16x4*)&Bs[buf][rowb * 72 + c4] = h;
      }
    };

    issueB(0, bA);
    issueB(1, bB);
    convert(0, 0, bA);
    sync_nodrain();
    for (int c = 1; c < 16; c += 2) {
      convert(1, c, bB);
      if (c + 1 < 16) issueB(c + 1, bA);
      sync_nodrain();
      if (c + 1 < 16) convert(0, c + 1, bA);
      if (c + 2 < 16) issueB(c + 2, bB);
      sync_nodrain();
    }
  } else {
    // -------- consumers --------
    const int cw = w - 4;
    f32x4 acc[8] = {};
    sync_nodrain();
    for (int c = 0; c < 16; ++c) {
      const short* Ab = &As[c & 1][0];
      const short* Bb = &Bs[c & 1][0];
#pragma unroll
      for (int kk = 0; kk < 64; kk += 32) {
        s16x8 a = *(const s16x8*)&Ab[(cw * 16 + l15) * 72 + kk + l4 * 8];
#pragma unroll
        for (int nf = 0; nf < 8; ++nf) {
          s16x8 b = *(const s16x8*)&Bb[(nf * 16 + l15) * 72 + kk + l4 * 8];
          acc[nf] = mfma16(a, b, acc[nf]);
        }
      }
      sync_nodrain();
    }
#pragma unroll
    for (int nf = 0; nf < 8; ++nf)
#pragma unroll
      for (int r = 0; r < 4; ++r)
        Cp[(size_t)(cw * 16 + l4 * 4 + r) * 4096 + nf * 16 + l15] = acc[nf][r];
  }
}

// ---- qkv split-K reduce + RoPE, writes q_buf / k_new / v_new ----
__global__ __launch_bounds__(256)
void rope_reduce(const float* __restrict__ part, const float* __restrict__ ctab,
                 const float* __restrict__ stab, float* __restrict__ q,
                 float* __restrict__ kn, float* __restrict__ vn) {
  int idx = blockIdx.x * 256 + threadIdx.x;   // < 786432 = 256*3072 pairs
  int m = idx / 3072;
  int col = (idx - m * 3072) * 2;
  const float* src = part + (size_t)m * 6144 + col;
  float a0 = 0.f, a1 = 0.f;
#pragma unroll
  for (int s = 0; s < 4; ++s) {
    a0 += src[(size_t)s * 1572864];
    a1 += src[(size_t)s * 1572864 + 1];
  }
  if (col < 5120) {
    int local = (col < 4096) ? col : col - 4096;
    int f = (local & 127) >> 1, t = m & 15;
    float c = ctab[t * 64 + f], sn = stab[t * 64 + f];
    float o0 = a0 * c - a1 * sn, o1 = a0 * sn + a1 * c;
    if (col < 4096) {
      q[(size_t)m * 4096 + col] = o0;
      q[(size_t)m * 4096 + col + 1] = o1;
    } else {
      kn[(size_t)m * 1024 + local] = o0;
      kn[(size_t)m * 1024 + local + 1] = o1;
    }
  } else {
    int local = col - 5120;
    vn[(size_t)m * 1024 + local] = a0;
    vn[(size_t)m * 1024 + local + 1] = a1;
  }
}

// ------- flash attention, producer/consumer, flat-max (m == 0) softmax ------
// (unchanged from R12/R13 — best attn, ~183 us)
__global__ __launch_bounds__(512)
__attribute__((amdgpu_waves_per_eu(4, 4)))
void attn7(const float* __restrict__ kc_, const float* __restrict__ vc_,
           const float* __restrict__ qb, const float* __restrict__ kn,
           const float* __restrict__ vn, const int* __restrict__ ipos,
           float* __restrict__ pO, float* __restrict__ pL) {
  __shared__ short Ks[2][32 * 128];   // [s][d], swizzle c4 ^= (s&7)<<3
  __shared__ short Vt[2][128 * 34];   // [d][s], pad 34
  __shared__ short Ps[4 * 16 * 40];   // per-consumer-wave [q][s], pad 40
  const int sh = blockIdx.x, g = blockIdx.y, b = blockIdx.z;
  const int tid = threadIdx.x, lane = tid & 63, w = tid >> 6;
  const int l15 = lane & 15, l4 = lane >> 4;
  const float scale = 0.08838834764831845f;  // 1/sqrt(128)
  const int sbase = sh * 2048;               // 64 chunks of 32 rows

  const float* kc_b = kc_ + (size_t)b * SEQ * 1024 + g * 128;
  const float* vc_b = vc_ + (size_t)b * SEQ * 1024 + g * 128;
  const float* kn_b = kn + (size_t)b * 16 * 1024 + g * 128;
  const float* vn_b = vn + (size_t)b * 16 * 1024 + g * 128;

  if (w < 4) {
    const int krow = tid >> 5, kc4 = (tid & 31) << 2;
    const int vcol = tid & 127, vhr = (tid >> 7) << 4;
    float4 kA[4], kB[4];
    float vA[16], vB[16];

    auto issue = [&](int cb, float4 (&kr)[4], float (&vr)[16]) {
      if (cb + 32 <= NEWBASE) {
#pragma unroll
        for (int i = 0; i < 4; ++i)
          kr[i] = *(const float4*)(kc_b + (size_t)(cb + krow + i * 8) * 1024 + kc4);
#pragma unroll
        for (int j = 0; j < 16; ++j)
          vr[j] = vc_b[(size_t)(cb + vhr + j) * 1024 + vcol];
      } else {
#pragma unroll
        for (int i = 0; i < 4; ++i) {
          int sg = cb + krow + i * 8;
          const float* src = (sg >= NEWBASE)
              ? (kn_b + (size_t)(sg - NEWBASE) * 1024 + kc4)
              : (kc_b + (size_t)sg * 1024 + kc4);
          kr[i] = *(const float4*)src;
        }
#pragma unroll
        for (int j = 0; j < 16; ++j) {
          int sg = cb + vhr + j;
          vr[j] = (sg >= NEWBASE)
              ? vn_b[(size_t)(sg - NEWBASE) * 1024 + vcol]
              : vc_b[(size_t)sg * 1024 + vcol];
        }
      }
    };
    auto convert = [&](int buf, const float4 (&kr)[4], const float (&vr)[16]) {
#pragma unroll
      for (int i = 0; i < 4; ++i) {
        int s = krow + i * 8;
        s16x4 hv = { f2bf(kr[i].x), f2bf(kr[i].y), f2bf(kr[i].z), f2bf(kr[i].w) };
        *(s16x4*)&Ks[buf][s * 128 + (kc4 ^ ((s & 7) << 3))] = hv;
      }
#pragma unroll
      for (int j4 = 0; j4 < 4; ++j4) {
        s16x4 hv = { f2bf(vr[j4 * 4]), f2bf(vr[j4 * 4 + 1]),
                     f2bf(vr[j4 * 4 + 2]), f2bf(vr[j4 * 4 + 3]) };
        *(s16x4*)&Vt[buf][vcol * 34 + vhr + j4 * 4] = hv;
      }
    };

    issue(sbase, kA, vA);
    issue(sbase + 32, kB, vB);
    convert(0, kA, vA);
    sync_nodrain();
    for (int c = 1; c < 64; c += 2) {
      convert(1, kB, vB);
      if (c + 1 < 64) issue(sbase + (c + 1) * 32, kA, vA);
      sync_nodrain();
      if (c + 1 < 64) convert(0, kA, vA);
      if (c + 2 < 64) issue(sbase + (c + 2) * 32, kB, vB);
      sync_nodrain();
    }
  } else {
    const int qg = w - 4;
    s16x8 qa[4];
    {
      int qr = qg * 16 + l15;
      int t = qr >> 2, r = qr & 3, h = g * 4 + r;
      const float* qp = qb + (size_t)(b * 16 + t) * 4096 + h * 128;
#pragma unroll
      for (int ks = 0; ks < 4; ++ks) {
        float4 v0 = *(const float4*)(qp + ks * 32 + l4 * 8);
        float4 v1 = *(const float4*)(qp + ks * 32 + l4 * 8 + 4);
        qa[ks] = s16x8{ f2bf(v0.x), f2bf(v0.y), f2bf(v0.z), f2bf(v0.w),
                        f2bf(v1.x), f2bf(v1.y), f2bf(v1.z), f2bf(v1.w) };
      }
    }
    const int ip_t = ipos[qg * 4 + l4];
    f32x4 o[8] = {};
    float lsum[4] = { 0.f, 0.f, 0.f, 0.f };
    short* Pw = &Ps[qg * (16 * 40)];

    sync_nodrain();
    for (int c = 0; c < 64; ++c) {
      const short* Kb = &Ks[c & 1][0];
      const short* Vb = &Vt[c & 1][0];
      const int base = sbase + c * 32;
      f32x4 sc[2] = {};
#pragma unroll
      for (int ks = 0; ks < 4; ++ks) {
        int dd = ks * 32 + l4 * 8;
#pragma unroll
        for (int nf = 0; nf < 2; ++nf) {
          int s = nf * 16 + l15;
          s16x8 kb = *(const s16x8*)&Kb[s * 128 + (dd ^ ((s & 7) << 3))];
          sc[nf] = mfma16(qa[ks], kb, sc[nf]);
        }
      }
#pragma unroll
      for (int nf = 0; nf < 2; ++nf) {
        int sg = base + nf * 16 + l15;
#pragma unroll
        for (int r = 0; r < 4; ++r) {
          float p = (sg <= ip_t) ? __expf(sc[nf][r] * scale) : 0.f;
          lsum[r] += p;
          Pw[(l4 * 4 + r) * 40 + nf * 16 + l15] = f2bf(p);
        }
      }
      s16x8 pa = *(const s16x8*)&Pw[l15 * 40 + l4 * 8];
#pragma unroll
      for (int nd = 0; nd < 8; ++nd) {
        int d = nd * 16 + l15;
        s16x8 vb = *(const s16x8*)&Vb[d * 34 + l4 * 8];
        o[nd] = mfma16(pa, vb, o[nd]);
      }
      sync_nodrain();
    }
#pragma unroll
    for (int r = 0; r < 4; ++r) {
      lsum[r] += __shfl_xor(lsum[r], 1, 64);
      lsum[r] += __shfl_xor(lsum[r], 2, 64);
      lsum[r] += __shfl_xor(lsum[r], 4, 64);
      lsum[r] += __shfl_xor(lsum[r], 8, 64);
    }
    const int blk = (b * 8 + g) * NS + sh;
    float* Ob = pO + (size_t)blk * 64 * 128;
#pragma unroll
    for (int nd = 0; nd < 8; ++nd)
#pragma unroll
      for (int r = 0; r < 4; ++r)
        Ob[(qg * 16 + l4 * 4 + r) * 128 + nd * 16 + l15] = o[nd][r];
    if (l15 == 0) {
#pragma unroll
      for (int r = 0; r < 4; ++r)
        pL[blk * 64 + qg * 16 + l4 * 4 + r] = lsum[r];
    }
  }
}

// ---- out-proj split-K reduce (4 partials) ----
__global__ __launch_bounds__(256)
void out_reduce(const float* __restrict__ part, float* __restrict__ out) {
  int i = blockIdx.x * 256 + threadIdx.x;   // < 262144 float4s
  const f32x4* p4 = (const f32x4*)part;
  f32x4 s = {0.f, 0.f, 0.f, 0.f};
#pragma unroll
  for (int sp = 0; sp < 4; ++sp) s += p4[(size_t)sp * 262144 + i];
  ((f32x4*)out)[i] = s;
}

extern "C" void kernel_launch(void* const* d_in, const int* in_sizes, int n_in,
                              void* d_out, int out_size, void* d_ws, size_t ws_size,
                              hipStream_t stream) {
  const float* x      = (const float*)d_in[0];
  const int*   ipos   = (const int*)d_in[3];
  const float* kcache = (const float*)d_in[5];
  const float* vcache = (const float*)d_in[6];
  const float* wq     = (const float*)d_in[7];
  const float* wk     = (const float*)d_in[8];
  const float* wv     = (const float*)d_in[9];
  const float* wo     = (const float*)d_in[10];
  float* out = (float*)d_out;

  float* q_buf = (float*)d_ws;            // 1048576
  float* k_new = q_buf + 1048576;         // 262144
  float* v_new = k_new + 262144;          // 262144
  float* y_buf = v_new + 262144;          // 1048576 (unused now)
  float* ctab  = y_buf + 1048576;         // 1024
  float* stab  = ctab + 1024;             // 1024
  float* pO    = stab + 1024;             // region 8388608 floats
  float* pL    = pO + 8388608;            // 32768 used
  float* qkvp  = pO;                      // alias: qkv partials (6.29M floats),
                                          //   dead before attn writes pO[0,4.19M)
  float* outp  = pO + 4194304;            // out partials: free 2nd half of region

  gemm_qkv<<<dim3(48, 4, 4), 512, 0, stream>>>(x, wq, wk, wv, qkvp,
                                               ipos, ctab, stab);
  rope_reduce<<<3072, 256, 0, stream>>>(qkvp, ctab, stab, q_buf, k_new, v_new);
  attn7<<<dim3(NS, 8, 16), 512, 0, stream>>>(kcache, vcache, q_buf, k_new, v_new,
                                             ipos, pO, pL);
  gemm_out_fused<<<dim3(32, 4, 4), 512, 0, stream>>>(pO, pL, wo, outp);
  out_reduce<<<1024, 256, 0, stream>>>(outp, out);
}

// Round 15
// 291.221 us; speedup vs baseline: 1.1501x; 1.1501x over previous
//
#include <hip/hip_runtime.h>
#include <math.h>

#define SEQ 8192
#define NEWBASE 8176     // SEQ - T
#define NS 4             // attn s-splits per (b, kv-head)

typedef short s16x4 __attribute__((ext_vector_type(4)));
typedef short s16x8 __attribute__((ext_vector_type(8)));
typedef float f32x4 __attribute__((ext_vector_type(4)));

__device__ __forceinline__ short f2bf(float f) {
  unsigned u = __float_as_uint(f);
  u += 0x7FFFu + ((u >> 16) & 1u);   // RNE
  return (short)(u >> 16);
}

__device__ __forceinline__ f32x4 mfma16(s16x8 a, s16x8 b, f32x4 c) {
  return __builtin_amdgcn_mfma_f32_16x16x32_bf16(a, b, c, 0, 0, 0);
}

// Workgroup barrier WITHOUT the vmcnt(0) drain of __syncthreads().
__device__ __forceinline__ void sync_nodrain() {
  __builtin_amdgcn_sched_barrier(0);
  asm volatile("s_waitcnt lgkmcnt(0)" ::: "memory");
  __builtin_amdgcn_s_barrier();
  __builtin_amdgcn_sched_barrier(0);
}

// ---- 64Mx128N tile GEMM, producer/consumer (attn7-style schedule) ----------
template<int KS>
__device__ __forceinline__
void gemm_tile_pc(const float* __restrict__ A, const float* __restrict__ Bw,
                  float* __restrict__ Cp, int ldc) {
  __shared__ short As[2][64 * 72];
  __shared__ short Bs[2][128 * 72];
  const int tid = threadIdx.x, lane = tid & 63, w = tid >> 6;
  const int l15 = lane & 15, l4 = lane >> 4;

  if (w < 4) {
    float4 aA[4], aB[4], bA[8], bB[8];
    auto issue = [&](int st, float4 (&ar)[4], float4 (&br)[8]) {
      const float* Ab = A + st * 64;
      const float* Bb = Bw + st * 64;
#pragma unroll
      for (int i = 0; i < 4; ++i) {
        int id = tid + i * 256;
        ar[i] = *(const float4*)(Ab + (size_t)(id >> 4) * 4096 + ((id & 15) << 2));
      }
#pragma unroll
      for (int i = 0; i < 8; ++i) {
        int id = tid + i * 256;
        br[i] = *(const float4*)(Bb + (size_t)(id >> 4) * 4096 + ((id & 15) << 2));
      }
    };
    auto convert = [&](int buf, const float4 (&ar)[4], const float4 (&br)[8]) {
#pragma unroll
      for (int i = 0; i < 4; ++i) {
        int id = tid + i * 256, row = id >> 4, c4 = (id & 15) << 2;
        s16x4 h = { f2bf(ar[i].x), f2bf(ar[i].y), f2bf(ar[i].z), f2bf(ar[i].w) };
        *(s16x4*)&As[buf][row * 72 + c4] = h;
      }
#pragma unroll
      for (int i = 0; i < 8; ++i) {
        int id = tid + i * 256, row = id >> 4, c4 = (id & 15) << 2;
        s16x4 h = { f2bf(br[i].x), f2bf(br[i].y), f2bf(br[i].z), f2bf(br[i].w) };
        *(s16x4*)&Bs[buf][row * 72 + c4] = h;
      }
    };

    issue(0, aA, bA);
    issue(1, aB, bB);
    convert(0, aA, bA);
    sync_nodrain();
    for (int c = 1; c < KS; c += 2) {
      convert(1, aB, bB);
      if (c + 1 < KS) issue(c + 1, aA, bA);
      sync_nodrain();
      if (c + 1 < KS) convert(0, aA, bA);
      if (c + 2 < KS) issue(c + 2, aB, bB);
      sync_nodrain();
    }
  } else {
    const int cw = w - 4;
    f32x4 acc[8] = {};
    sync_nodrain();
    for (int c = 0; c < KS; ++c) {
      const short* Ab = &As[c & 1][0];
      const short* Bb = &Bs[c & 1][0];
#pragma unroll
      for (int kk = 0; kk < 64; kk += 32) {
        s16x8 a = *(const s16x8*)&Ab[(cw * 16 + l15) * 72 + kk + l4 * 8];
#pragma unroll
        for (int nf = 0; nf < 8; ++nf) {
          s16x8 b = *(const s16x8*)&Bb[(nf * 16 + l15) * 72 + kk + l4 * 8];
          acc[nf] = mfma16(a, b, acc[nf]);
        }
      }
      sync_nodrain();
    }
#pragma unroll
    for (int nf = 0; nf < 8; ++nf)
#pragma unroll
      for (int r = 0; r < 4; ++r)
        Cp[(size_t)(cw * 16 + l4 * 4 + r) * ldc + nf * 16 + l15] = acc[nf][r];
  }
}

// fused QKV: grid (48, 4, 2), split-K = 2; block (0,0,0) builds RoPE tables
__global__ __launch_bounds__(512)
__attribute__((amdgpu_waves_per_eu(4, 4)))
void gemm_qkv(const float* __restrict__ x,
              const float* __restrict__ wq, const float* __restrict__ wk,
              const float* __restrict__ wv, float* __restrict__ part,
              const int* __restrict__ ipos,
              float* __restrict__ ctab, float* __restrict__ stab) {
  int bn = blockIdx.x, bm = blockIdx.y, sp = blockIdx.z;
  if (bn == 0 && bm == 0 && sp == 0) {
#pragma unroll
    for (int k = 0; k < 2; ++k) {
      int i = threadIdx.x + k * 512;       // 1024: t*64 + f
      int t = i >> 6, f = i & 63;
      double inv = exp(-((double)(2 * f) / 128.0) * log(500000.0));
      double ang = (double)ipos[t] * inv;
      ctab[i] = (float)cos(ang);
      stab[i] = (float)sin(ang);
    }
  }
  const float* Bw;
  if (bn < 32)      Bw = wq + (size_t)(bn * 128) * 4096;
  else if (bn < 40) Bw = wk + (size_t)((bn - 32) * 128) * 4096;
  else              Bw = wv + (size_t)((bn - 40) * 128) * 4096;
  const float* A = x + (size_t)(bm * 64) * 4096 + sp * 2048;
  float* Cp = part + (size_t)sp * (256 * 6144) + (size_t)(bm * 64) * 6144 + bn * 128;
  gemm_tile_pc<32>(A, Bw + sp * 2048, Cp, 6144);
}

// out projection: grid (32, 4, 2), split-K = 2
__global__ __launch_bounds__(512)
__attribute__((amdgpu_waves_per_eu(4, 4)))
void gemm_out(const float* __restrict__ y, const float* __restrict__ wo,
              float* __restrict__ part) {
  int bn = blockIdx.x, bm = blockIdx.y, sp = blockIdx.z;
  const float* A = y + (size_t)(bm * 64) * 4096 + sp * 2048;
  const float* Bw = wo + (size_t)(bn * 128) * 4096 + sp * 2048;
  float* Cp = part + (size_t)sp * (256 * 4096) + (size_t)(bm * 64) * 4096 + bn * 128;
  gemm_tile_pc<32>(A, Bw, Cp, 4096);
}

// ---- qkv split-K reduce (2 partials) + RoPE -> q_buf / k_new / v_new ----
__global__ __launch_bounds__(256)
void rope_reduce(const float* __restrict__ part, const float* __restrict__ ctab,
                 const float* __restrict__ stab, float* __restrict__ q,
                 float* __restrict__ kn, float* __restrict__ vn) {
  int idx = blockIdx.x * 256 + threadIdx.x;   // < 786432 = 256*3072 pairs
  int m = idx / 3072;
  int col = (idx - m * 3072) * 2;
  const float* src = part + (size_t)m * 6144 + col;
  float a0 = src[0] + src[1572864];
  float a1 = src[1] + src[1572865];
  if (col < 5120) {
    int local = (col < 4096) ? col : col - 4096;
    int f = (local & 127) >> 1, t = m & 15;
    float c = ctab[t * 64 + f], sn = stab[t * 64 + f];
    float o0 = a0 * c - a1 * sn, o1 = a0 * sn + a1 * c;
    if (col < 4096) {
      q[(size_t)m * 4096 + col] = o0;
      q[(size_t)m * 4096 + col + 1] = o1;
    } else {
      kn[(size_t)m * 1024 + local] = o0;
      kn[(size_t)m * 1024 + local + 1] = o1;
    }
  } else {
    int local = col - 5120;
    vn[(size_t)m * 1024 + local] = a0;
    vn[(size_t)m * 1024 + local + 1] = a1;
  }
}

// ------- flash attention, producer/consumer, flat-max (m == 0) softmax ------
// (unchanged from R12/R13 — best attn, ~183 us)
__global__ __launch_bounds__(512)
__attribute__((amdgpu_waves_per_eu(4, 4)))
void attn7(const float* __restrict__ kc_, const float* __restrict__ vc_,
           const float* __restrict__ qb, const float* __restrict__ kn,
           const float* __restrict__ vn, const int* __restrict__ ipos,
           float* __restrict__ pO, float* __restrict__ pL) {
  __shared__ short Ks[2][32 * 128];   // [s][d], swizzle c4 ^= (s&7)<<3
  __shared__ short Vt[2][128 * 34];   // [d][s], pad 34
  __shared__ short Ps[4 * 16 * 40];   // per-consumer-wave [q][s], pad 40
  const int sh = blockIdx.x, g = blockIdx.y, b = blockIdx.z;
  const int tid = threadIdx.x, lane = tid & 63, w = tid >> 6;
  const int l15 = lane & 15, l4 = lane >> 4;
  const float scale = 0.08838834764831845f;  // 1/sqrt(128)
  const int sbase = sh * 2048;               // 64 chunks of 32 rows

  const float* kc_b = kc_ + (size_t)b * SEQ * 1024 + g * 128;
  const float* vc_b = vc_ + (size_t)b * SEQ * 1024 + g * 128;
  const float* kn_b = kn + (size_t)b * 16 * 1024 + g * 128;
  const float* vn_b = vn + (size_t)b * 16 * 1024 + g * 128;

  if (w < 4) {
    const int krow = tid >> 5, kc4 = (tid & 31) << 2;
    const int vcol = tid & 127, vhr = (tid >> 7) << 4;
    float4 kA[4], kB[4];
    float vA[16], vB[16];

    auto issue = [&](int cb, float4 (&kr)[4], float (&vr)[16]) {
      if (cb + 32 <= NEWBASE) {
#pragma unroll
        for (int i = 0; i < 4; ++i)
          kr[i] = *(const float4*)(kc_b + (size_t)(cb + krow + i * 8) * 1024 + kc4);
#pragma unroll
        for (int j = 0; j < 16; ++j)
          vr[j] = vc_b[(size_t)(cb + vhr + j) * 1024 + vcol];
      } else {
#pragma unroll
        for (int i = 0; i < 4; ++i) {
          int sg = cb + krow + i * 8;
          const float* src = (sg >= NEWBASE)
              ? (kn_b + (size_t)(sg - NEWBASE) * 1024 + kc4)
              : (kc_b + (size_t)sg * 1024 + kc4);
          kr[i] = *(const float4*)src;
        }
#pragma unroll
        for (int j = 0; j < 16; ++j) {
          int sg = cb + vhr + j;
          vr[j] = (sg >= NEWBASE)
              ? vn_b[(size_t)(sg - NEWBASE) * 1024 + vcol]
              : vc_b[(size_t)sg * 1024 + vcol];
        }
      }
    };
    auto convert = [&](int buf, const float4 (&kr)[4], const float (&vr)[16]) {
#pragma unroll
      for (int i = 0; i < 4; ++i) {
        int s = krow + i * 8;
        s16x4 hv = { f2bf(kr[i].x), f2bf(kr[i].y), f2bf(kr[i].z), f2bf(kr[i].w) };
        *(s16x4*)&Ks[buf][s * 128 + (kc4 ^ ((s & 7) << 3))] = hv;
      }
#pragma unroll
      for (int j4 = 0; j4 < 4; ++j4) {
        s16x4 hv = { f2bf(vr[j4 * 4]), f2bf(vr[j4 * 4 + 1]),
                     f2bf(vr[j4 * 4 + 2]), f2bf(vr[j4 * 4 + 3]) };
        *(s16x4*)&Vt[buf][vcol * 34 + vhr + j4 * 4] = hv;
      }
    };

    issue(sbase, kA, vA);
    issue(sbase + 32, kB, vB);
    convert(0, kA, vA);
    sync_nodrain();
    for (int c = 1; c < 64; c += 2) {
      convert(1, kB, vB);
      if (c + 1 < 64) issue(sbase + (c + 1) * 32, kA, vA);
      sync_nodrain();
      if (c + 1 < 64) convert(0, kA, vA);
      if (c + 2 < 64) issue(sbase + (c + 2) * 32, kB, vB);
      sync_nodrain();
    }
  } else {
    const int qg = w - 4;
    s16x8 qa[4];
    {
      int qr = qg * 16 + l15;
      int t = qr >> 2, r = qr & 3, h = g * 4 + r;
      const float* qp = qb + (size_t)(b * 16 + t) * 4096 + h * 128;
#pragma unroll
      for (int ks = 0; ks < 4; ++ks) {
        float4 v0 = *(const float4*)(qp + ks * 32 + l4 * 8);
        float4 v1 = *(const float4*)(qp + ks * 32 + l4 * 8 + 4);
        qa[ks] = s16x8{ f2bf(v0.x), f2bf(v0.y), f2bf(v0.z), f2bf(v0.w),
                        f2bf(v1.x), f2bf(v1.y), f2bf(v1.z), f2bf(v1.w) };
      }
    }
    const int ip_t = ipos[qg * 4 + l4];
    f32x4 o[8] = {};
    float lsum[4] = { 0.f, 0.f, 0.f, 0.f };
    short* Pw = &Ps[qg * (16 * 40)];

    sync_nodrain();
    for (int c = 0; c < 64; ++c) {
      const short* Kb = &Ks[c & 1][0];
      const short* Vb = &Vt[c & 1][0];
      const int base = sbase + c * 32;
      f32x4 sc[2] = {};
#pragma unroll
      for (int ks = 0; ks < 4; ++ks) {
        int dd = ks * 32 + l4 * 8;
#pragma unroll
        for (int nf = 0; nf < 2; ++nf) {
          int s = nf * 16 + l15;
          s16x8 kb = *(const s16x8*)&Kb[s * 128 + (dd ^ ((s & 7) << 3))];
          sc[nf] = mfma16(qa[ks], kb, sc[nf]);
        }
      }
#pragma unroll
      for (int nf = 0; nf < 2; ++nf) {
        int sg = base + nf * 16 + l15;
#pragma unroll
        for (int r = 0; r < 4; ++r) {
          float p = (sg <= ip_t) ? __expf(sc[nf][r] * scale) : 0.f;
          lsum[r] += p;
          Pw[(l4 * 4 + r) * 40 + nf * 16 + l15] = f2bf(p);
        }
      }
      s16x8 pa = *(const s16x8*)&Pw[l15 * 40 + l4 * 8];
#pragma unroll
      for (int nd = 0; nd < 8; ++nd) {
        int d = nd * 16 + l15;
        s16x8 vb = *(const s16x8*)&Vb[d * 34 + l4 * 8];
        o[nd] = mfma16(pa, vb, o[nd]);
      }
      sync_nodrain();
    }
#pragma unroll
    for (int r = 0; r < 4; ++r) {
      lsum[r] += __shfl_xor(lsum[r], 1, 64);
      lsum[r] += __shfl_xor(lsum[r], 2, 64);
      lsum[r] += __shfl_xor(lsum[r], 4, 64);
      lsum[r] += __shfl_xor(lsum[r], 8, 64);
    }
    const int blk = (b * 8 + g) * NS + sh;
    float* Ob = pO + (size_t)blk * 64 * 128;
#pragma unroll
    for (int nd = 0; nd < 8; ++nd)
#pragma unroll
      for (int r = 0; r < 4; ++r)
        Ob[(qg * 16 + l4 * 4 + r) * 128 + nd * 16 + l15] = o[nd][r];
    if (l15 == 0) {
#pragma unroll
      for (int r = 0; r < 4; ++r)
        pL[blk * 64 + qg * 16 + l4 * 4 + r] = lsum[r];
    }
  }
}

// ------- merge the NS s-splits (m == 0 -> plain sums), 512 blocks ----------
__global__ __launch_bounds__(256)
void merge(const float* __restrict__ pO, const float* __restrict__ pL,
           float* __restrict__ y) {
  const int gq = blockIdx.x, b = blockIdx.y;
  const int g = gq >> 2, qc = gq & 3;
  const int bb = (b * 8 + g) * NS;
#pragma unroll
  for (int i = 0; i < 8; ++i) {
    int id = qc * 2048 + i * 256 + threadIdx.x;   // 0..8191 within (g,b)
    int qr = id >> 7, d = id & 127;
    float acc = 0.f, den = 0.f;
#pragma unroll
    for (int p = 0; p < NS; ++p) {
      acc += pO[(size_t)(bb + p) * 8192 + id];
      den += pL[(bb + p) * 64 + qr];
    }
    int t = qr >> 2, r = qr & 3, h = g * 4 + r;
    y[(size_t)(b * 16 + t) * 4096 + h * 128 + d] = acc / den;
  }
}

// ---- out-proj split-K reduce (2 partials) ----
__global__ __launch_bounds__(256)
void out_reduce(const float* __restrict__ part, float* __restrict__ out) {
  int i = blockIdx.x * 256 + threadIdx.x;   // < 262144 float4s
  const f32x4* p4 = (const f32x4*)part;
  f32x4 s = p4[i] + p4[(size_t)262144 + i];
  ((f32x4*)out)[i] = s;
}

extern "C" void kernel_launch(void* const* d_in, const int* in_sizes, int n_in,
                              void* d_out, int out_size, void* d_ws, size_t ws_size,
                              hipStream_t stream) {
  const float* x      = (const float*)d_in[0];
  const int*   ipos   = (const int*)d_in[3];
  const float* kcache = (const float*)d_in[5];
  const float* vcache = (const float*)d_in[6];
  const float* wq     = (const float*)d_in[7];
  const float* wk     = (const float*)d_in[8];
  const float* wv     = (const float*)d_in[9];
  const float* wo     = (const float*)d_in[10];
  float* out = (float*)d_out;

  float* q_buf = (float*)d_ws;            // 1048576
  float* k_new = q_buf + 1048576;         // 262144
  float* v_new = k_new + 262144;          // 262144
  float* y_buf = v_new + 262144;          // 1048576
  float* ctab  = y_buf + 1048576;         // 1024
  float* stab  = ctab + 1024;             // 1024
  float* pO    = stab + 1024;             // region 8388608 floats
  float* pL    = pO + 8388608;            // 32768 used
  float* qkvp  = pO;                      // alias: qkv partials (3.15M floats),
                                          //   dead before attn writes pO[0,4.19M)
  float* outp  = pO + 4194304;            // out partials (2.1M): free 2nd half

  gemm_qkv<<<dim3(48, 4, 2), 512, 0, stream>>>(x, wq, wk, wv, qkvp,
                                               ipos, ctab, stab);
  rope_reduce<<<3072, 256, 0, stream>>>(qkvp, ctab, stab, q_buf, k_new, v_new);
  attn7<<<dim3(NS, 8, 16), 512, 0, stream>>>(kcache, vcache, q_buf, k_new, v_new,
                                             ipos, pO, pL);
  merge<<<dim3(32, 16), 256, 0, stream>>>(pO, pL, y_buf);
  gemm_out<<<dim3(32, 4, 2), 512, 0, stream>>>(y_buf, wo, outp);
  out_reduce<<<1024, 256, 0, stream>>>(outp, out);
}